// Round 19
// baseline (191.640 us; speedup 1.0000x reference)
//
#include <hip/hip_runtime.h>
#include <hip/hip_fp16.h>
#include <math.h>

#define NNODES 40000
#define NEDGES 640000
#define NETOT  (NEDGES + NNODES)
#define HC 128     // heads*channels
#define OUTC 32
#define NBLK   ((NNODES + 255) / 256)   // 157 scan blocks

typedef __attribute__((ext_vector_type(8))) _Float16 v8h;
typedef __attribute__((ext_vector_type(2))) _Float16 v2h;
typedef __attribute__((ext_vector_type(4))) float    v4f;

__device__ __forceinline__ v2h h2bits(unsigned u)
{
    union { unsigned u; v2h h; } c; c.u = u; return c.h;
}
__device__ __forceinline__ float h_lo(unsigned u)
{
    return __half2float(__ushort_as_half((unsigned short)(u & 0xffff)));
}
__device__ __forceinline__ unsigned splat_h(float f)
{
    unsigned short h = __half_as_ushort(__float2half(f));
    return ((unsigned)h << 16) | h;
}

// ---------------------------------------------------------------------------
// Phase 0 (FUSED): blocks [0, CB) do per-dst counts + slot record;
// blocks [CB, ...) convert x / W matrices to fp16.
// ---------------------------------------------------------------------------
#define CB ((NEDGES + 255) / 256)                    // 2500 count blocks
#define SX4 (NNODES * 64 / 4)                        // float4 groups of x
#define CONV (SX4 + 2 * 128 * 64 + 2 * 128 * 128)    // convert elements

__global__ void count_convert_kernel(const int* __restrict__ dst, int* __restrict__ cnt,
                                     int* __restrict__ slot,
                                     const float* __restrict__ x,
                                     const float* __restrict__ Wl1, const float* __restrict__ Wr1,
                                     const float* __restrict__ Wl2, const float* __restrict__ Wr2,
                                     __half* __restrict__ x16,
                                     __half* __restrict__ WH1, __half* __restrict__ WH2)
{
    int b = blockIdx.x;
    if (b < CB) {
        int e = b * 256 + threadIdx.x;
        if (e >= NEDGES) return;
        slot[e] = atomicAdd(&cnt[dst[e]], 1);
        return;
    }
    int i = (b - CB) * 256 + threadIdx.x;
    if (i < SX4) {
        float4 v = ((const float4*)x)[i];
        __half tmp[4] = {__float2half(v.x), __float2half(v.y),
                         __float2half(v.z), __float2half(v.w)};
        ((uint2*)x16)[i] = *(const uint2*)tmp;
        return;
    }
    int j = i - SX4;
    if (j < 128 * 64)            { WH1[j] = __float2half(Wl1[j]); return; }
    j -= 128 * 64;
    if (j < 128 * 64)            { WH1[128 * 64 + j] = __float2half(Wr1[j]); return; }
    j -= 128 * 64;
    if (j < 128 * 128)           { WH2[j] = __float2half(Wl2[j]); return; }
    j -= 128 * 128;
    if (j < 128 * 128)           { WH2[128 * 128 + j] = __float2half(Wr2[j]); return; }
}

// ---------------------------------------------------------------------------
// Two-level exclusive scan of (cnt[n]+1) over 40000 nodes (+1 self loop).
// ---------------------------------------------------------------------------
__global__ __launch_bounds__(256) void scan1_kernel(const int* __restrict__ cnt,
                                                    int* __restrict__ offsets,
                                                    int* __restrict__ blocksum)
{
    __shared__ int s[256];
    int t = threadIdx.x;
    int n = blockIdx.x * 256 + t;
    int v = (n < NNODES) ? (cnt[n] + 1) : 0;
    s[t] = v;
    __syncthreads();
    for (int off = 1; off < 256; off <<= 1) {
        int u = (t >= off) ? s[t - off] : 0;
        __syncthreads();
        s[t] += u;
        __syncthreads();
    }
    if (n < NNODES) offsets[n] = s[t] - v;     // exclusive local prefix
    if (t == 255) blocksum[blockIdx.x] = s[255];
}

__global__ __launch_bounds__(256) void scan2_kernel(int* __restrict__ blocksum)
{
    __shared__ int s[256];
    int t = threadIdx.x;
    int v = (t < NBLK) ? blocksum[t] : 0;
    s[t] = v;
    __syncthreads();
    for (int off = 1; off < 256; off <<= 1) {
        int u = (t >= off) ? s[t - off] : 0;
        __syncthreads();
        s[t] += u;
        __syncthreads();
    }
    if (t < NBLK) blocksum[t] = s[t] - v;      // exclusive
}

__global__ __launch_bounds__(256) void scan3_kernel(int* __restrict__ offsets,
                                                    const int* __restrict__ blocksum)
{
    int n = blockIdx.x * 256 + threadIdx.x;
    if (n >= NNODES) return;
    offsets[n] += blocksum[blockIdx.x];
    if (n == 0) offsets[NNODES] = NETOT;
}

// ---------------------------------------------------------------------------
// MFMA node transform body: D[chan][node] = W(fp16)[chan][k] . X(fp16)[node][k]
// ---------------------------------------------------------------------------
template <int K>
__device__ __forceinline__ void transform_body(
    int bx, int t,
    const __half* __restrict__ X16, const __half* __restrict__ WH,
    const float* __restrict__ bl, const float* __restrict__ br,
    __half* __restrict__ XLo, __half* __restrict__ XRo)
{
    int w = t >> 6, lane = t & 63;
    int nb = bx * 32;
    int mb = w * 64;                 // channel base of this wave (0..192)
    int l15 = lane & 15, lg = lane >> 4;

    v4f acc[4][2];
#pragma unroll
    for (int mt = 0; mt < 4; mt++)
#pragma unroll
        for (int nt = 0; nt < 2; nt++) acc[mt][nt] = (v4f){0.f, 0.f, 0.f, 0.f};

#pragma unroll
    for (int kb = 0; kb < K; kb += 32) {
        int kf = kb + lg * 8;
        v8h bfr[2], afr[4];
#pragma unroll
        for (int nt = 0; nt < 2; nt++)
            bfr[nt] = *(const v8h*)&X16[(size_t)(nb + nt * 16 + l15) * K + kf];
#pragma unroll
        for (int mt = 0; mt < 4; mt++)
            afr[mt] = *(const v8h*)&WH[(size_t)(mb + mt * 16 + l15) * K + kf];
#pragma unroll
        for (int mt = 0; mt < 4; mt++)
#pragma unroll
            for (int nt = 0; nt < 2; nt++)
                acc[mt][nt] = __builtin_amdgcn_mfma_f32_16x16x32_f16(
                    afr[mt], bfr[nt], acc[mt][nt], 0, 0, 0);
    }

    bool isR = mb >= 128;                  // wave-uniform
    const float* bias = isR ? br : bl;
    __half* Out       = isR ? XRo : XLo;
    int cb = (mb & 127);
#pragma unroll
    for (int mt = 0; mt < 4; mt++) {
        int cc = cb + mt * 16 + lg * 4;    // 4 consecutive channels
        float b0 = bias[cc], b1 = bias[cc + 1], b2 = bias[cc + 2], b3 = bias[cc + 3];
#pragma unroll
        for (int nt = 0; nt < 2; nt++) {
            int n = nb + nt * 16 + l15;
            __half tmp[4] = {__float2half(acc[mt][nt][0] + b0),
                             __float2half(acc[mt][nt][1] + b1),
                             __float2half(acc[mt][nt][2] + b2),
                             __float2half(acc[mt][nt][3] + b3)};
            *(uint2*)&Out[(size_t)n * HC + cc] = *(const uint2*)tmp;
        }
    }
}

template <int K>
__global__ __launch_bounds__(256) void transform_mfma_kernel(
    const __half* __restrict__ X16, const __half* __restrict__ WH,
    const float* __restrict__ bl, const float* __restrict__ br,
    __half* __restrict__ XLo, __half* __restrict__ XRo)
{
    transform_body<K>(blockIdx.x, threadIdx.x, X16, WH, bl, br, XLo, XRo);
}

// ---------------------------------------------------------------------------
// Phase 2 (FUSED with layer-1 transform): blocks [0, CB) place real edges
// ATOMIC-FREE into CSR-by-dst as 16B uint4 records
//   {src, splat16(e0), splat16(e1), splat16(e2)}
// (pre-splatted halves -> ZERO decode ops in agg's per-lane path).
// Blocks [CB, CB+1250) run the K=64 MFMA transform.
// Self loop of node n goes to slot offsets[n+1]-1, written by loopattr.
// ---------------------------------------------------------------------------
__global__ __launch_bounds__(256) void place_transform_kernel(
    const int* __restrict__ src, const int* __restrict__ dst,
    const float* __restrict__ eattr,
    const int* __restrict__ offsets, const int* __restrict__ slot,
    uint4* __restrict__ csr4,
    const __half* __restrict__ X16, const __half* __restrict__ WH,
    const float* __restrict__ bl, const float* __restrict__ br,
    __half* __restrict__ XLo, __half* __restrict__ XRo)
{
    int b = blockIdx.x;
    if (b < CB) {
        int e = b * 256 + threadIdx.x;
        if (e >= NEDGES) return;
        int d = dst[e];
        int pos = offsets[d] + slot[e];
        uint4 rec;
        rec.x = (unsigned)src[e];
        rec.y = splat_h(eattr[e * 3 + 0]);
        rec.z = splat_h(eattr[e * 3 + 1]);
        rec.w = splat_h(eattr[e * 3 + 2]);
        csr4[pos] = rec;
        return;
    }
    transform_body<64>(b - CB, threadIdx.x, X16, WH, bl, br, XLo, XRo);
}

// ---------------------------------------------------------------------------
// Phase 3: self-loop attr = mean of incoming edge attrs (PyG fill='mean'),
// written to the known last slot of each node's segment.
// ---------------------------------------------------------------------------
__global__ __launch_bounds__(256) void loopattr_kernel(const int* __restrict__ offsets,
                                                       uint4* __restrict__ csr4)
{
    int n = blockIdx.x * 256 + threadIdx.x;
    if (n >= NNODES) return;
    int beg = offsets[n], endr = offsets[n + 1] - 1;   // real edges [beg, endr)
    float s0 = 0.f, s1 = 0.f, s2 = 0.f;
    for (int j = beg; j < endr; j++) {
        uint4 q = csr4[j];
        s0 += h_lo(q.y); s1 += h_lo(q.z); s2 += h_lo(q.w);
    }
    int c = endr - beg;
    float inv = (c > 0) ? (1.0f / (float)c) : 0.0f;   // where(cnt>0, sum/cnt, 0)
    uint4 rec;
    rec.x = (unsigned)n;
    rec.y = splat_h(s0 * inv);
    rec.z = splat_h(s1 * inv);
    rec.w = splat_h(s2 * inv);
    csr4[endr] = rec;
}

// ---------------------------------------------------------------------------
// Cross-lane helpers, all DPP (VALU pipe, no lgkm wait).
// ---------------------------------------------------------------------------
template <int CTRL>
__device__ __forceinline__ float dpp_swap(float x)
{
    return __int_as_float(__builtin_amdgcn_update_dpp(
        0, __float_as_int(x), CTRL, 0xF, 0xF, true));
}

// ---------------------------------------------------------------------------
// GATv2 attention + aggregation: TWO EDGES PER WAVE-STEP.
// Lane l: half = l>>5 picks edge {A,B} of a pair; lp = l&31 owns 4 channels
// c0 = lp*4..+3 (head h = lp>>2, 4 lanes/head -> 2 quad-perm DPP reduce).
// Per-pair: one per-lane uint4 record load (broadcast within half, ZERO
// decode ops thanks to pre-splatted attrs), one 8B XL gather, packed-fp16
// logit math, one exp2. ~11 wave-ops/edge vs ~17 in the 1-edge scheme.
// f32 accumulators merged across halves with 5 shfl_xor(32) in epilogue.
// ---------------------------------------------------------------------------
template <int FUSE>
__global__ __launch_bounds__(256) void agg_kernel(
    const __half* __restrict__ XL, const __half* __restrict__ XR,
    const uint4* __restrict__ csr4, const int* __restrict__ offsets,
    const float* __restrict__ We, const float* __restrict__ att,
    const float* __restrict__ bias, __half* __restrict__ OUT,
    const float* __restrict__ Wf, const float* __restrict__ bf,
    float* __restrict__ out2)
{
    __shared__ float wf_s[FUSE ? OUTC * 132 : 1];   // pad 132 keeps rows 16B-aligned
    __shared__ float hrow[FUSE ? 4 * HC : 1];

    int t = threadIdx.x;
    if (FUSE) {
        for (int i = t * 4; i < OUTC * HC; i += 1024) {       // float4 staging
            float4 v = *(const float4*)&Wf[i];
            *(float4*)&wf_s[(i >> 7) * 132 + (i & 127)] = v;
        }
        __syncthreads();   // at kernel start: zero skew
    }

    int w = t >> 6;
    int n = __builtin_amdgcn_readfirstlane(blockIdx.x * 4 + w);
    int lane = t & 63;
    int half = lane >> 5;        // edge A / B of the pair
    int lp   = lane & 31;        // channel-group position
    int c0   = lp * 4;           // 4 channels

    const float LOG2E = 1.44269504088896340736f;
    uint2 xru = *(const uint2*)&XR[(size_t)n * HC + c0];
    v2h xr2a = h2bits(xru.x), xr2b = h2bits(xru.y);
    v2h at2a = {(_Float16)(att[c0 + 0] * LOG2E), (_Float16)(att[c0 + 1] * LOG2E)};
    v2h at2b = {(_Float16)(att[c0 + 2] * LOG2E), (_Float16)(att[c0 + 3] * LOG2E)};
    int cb3 = c0 * 3;
    v2h we0a = {(_Float16)We[cb3 + 0], (_Float16)We[cb3 + 3]};
    v2h we1a = {(_Float16)We[cb3 + 1], (_Float16)We[cb3 + 4]};
    v2h we2a = {(_Float16)We[cb3 + 2], (_Float16)We[cb3 + 5]};
    v2h we0b = {(_Float16)We[cb3 + 6], (_Float16)We[cb3 + 9]};
    v2h we1b = {(_Float16)We[cb3 + 7], (_Float16)We[cb3 + 10]};
    v2h we2b = {(_Float16)We[cb3 + 8], (_Float16)We[cb3 + 11]};
    const v2h vk02 = {(_Float16)0.2f, (_Float16)0.2f};

    int beg = offsets[n], end = offsets[n + 1];

    float dacc[4], a0[4], a1[4], a2[4], a3[4];
#pragma unroll
    for (int i = 0; i < 4; i++) { dacc[i] = 0.f; a0[i] = 0.f; a1[i] = 0.f; a2[i] = 0.f; a3[i] = 0.f; }

#define PAIR_STEP(qv, xlu, d_, A0, A1, A2, A3, ZTAIL)                          \
    {                                                                          \
        v2h xla = h2bits(xlu.x), xlb = h2bits(xlu.y);                          \
        v2h ma = xla + xr2a;                                                   \
        v2h mb = xlb + xr2b;                                                   \
        ma += we0a * h2bits(qv.y);  mb += we0b * h2bits(qv.y);                 \
        ma += we1a * h2bits(qv.z);  mb += we1b * h2bits(qv.z);                 \
        ma += we2a * h2bits(qv.w);  mb += we2b * h2bits(qv.w);                 \
        ma = __builtin_elementwise_max(ma, ma * vk02);                         \
        mb = __builtin_elementwise_max(mb, mb * vk02);                         \
        float p = __builtin_amdgcn_fdot2(mb, at2b, 0.0f, false);               \
        p = __builtin_amdgcn_fdot2(ma, at2a, p, false);                        \
        p += dpp_swap<0xB1>(p);                                                \
        p += dpp_swap<0x4E>(p);                                                \
        float ex = exp2f(p);                                                   \
        if (ZTAIL) ex = (half == 0) ? ex : 0.f;                                \
        d_ += ex;                                                              \
        A0 = fmaf(ex, (float)xla.x, A0);                                       \
        A1 = fmaf(ex, (float)xla.y, A1);                                       \
        A2 = fmaf(ex, (float)xlb.x, A2);                                       \
        A3 = fmaf(ex, (float)xlb.y, A3);                                       \
    }

    int j = beg;
    for (; j + 7 < end; j += 8) {                       // 4 pairs = 8 edges
        uint4 q[4]; uint2 xlu[4];
#pragma unroll
        for (int i = 0; i < 4; i++) q[i] = csr4[j + 2 * i + half];
#pragma unroll
        for (int i = 0; i < 4; i++)
            xlu[i] = *(const uint2*)&XL[((size_t)q[i].x << 7) + c0];
#pragma unroll
        for (int i = 0; i < 4; i++)
            PAIR_STEP(q[i], xlu[i], dacc[i], a0[i], a1[i], a2[i], a3[i], false);
    }
    if (j + 3 < end) {                                   // 2 pairs = 4 edges
        uint4 q[2]; uint2 xlu[2];
#pragma unroll
        for (int i = 0; i < 2; i++) q[i] = csr4[j + 2 * i + half];
#pragma unroll
        for (int i = 0; i < 2; i++)
            xlu[i] = *(const uint2*)&XL[((size_t)q[i].x << 7) + c0];
#pragma unroll
        for (int i = 0; i < 2; i++)
            PAIR_STEP(q[i], xlu[i], dacc[i], a0[i], a1[i], a2[i], a3[i], false);
        j += 4;
    }
    if (j + 1 < end) {                                   // 1 pair = 2 edges
        uint4 q = csr4[j + half];
        uint2 xlu = *(const uint2*)&XL[((size_t)q.x << 7) + c0];
        PAIR_STEP(q, xlu, dacc[0], a0[0], a1[0], a2[0], a3[0], false);
        j += 2;
    }
    if (j < end) {                                       // single tail edge
        uint4 q = csr4[j];                               // both halves same rec
        uint2 xlu = *(const uint2*)&XL[((size_t)q.x << 7) + c0];
        PAIR_STEP(q, xlu, dacc[0], a0[0], a1[0], a2[0], a3[0], true);
    }
#undef PAIR_STEP

    float den  = (dacc[0] + dacc[1]) + (dacc[2] + dacc[3]);
    float s0 = (a0[0] + a0[1]) + (a0[2] + a0[3]);
    float s1 = (a1[0] + a1[1]) + (a1[2] + a1[3]);
    float s2 = (a2[0] + a2[1]) + (a2[2] + a2[3]);
    float s3 = (a3[0] + a3[1]) + (a3[2] + a3[3]);

    // merge the two halves (A-edges in lanes 0-31, B-edges in 32-63)
    den += __shfl_xor(den, 32);
    s0  += __shfl_xor(s0, 32);
    s1  += __shfl_xor(s1, 32);
    s2  += __shfl_xor(s2, 32);
    s3  += __shfl_xor(s3, 32);

    float inv = 1.0f / (den + 1e-16f);
    float o0 = s0 * inv + bias[c0 + 0];
    float o1 = s1 * inv + bias[c0 + 1];
    float o2 = s2 * inv + bias[c0 + 2];
    float o3 = s3 * inv + bias[c0 + 3];
    o0 = (o0 > 0.f) ? o0 : expm1f(o0);   // ELU (both layers)
    o1 = (o1 > 0.f) ? o1 : expm1f(o1);
    o2 = (o2 > 0.f) ? o2 : expm1f(o2);
    o3 = (o3 > 0.f) ? o3 : expm1f(o3);

    if (!FUSE) {
        if (half == 0) {
            __half tmp[4] = {__float2half(o0), __float2half(o1),
                             __float2half(o2), __float2half(o3)};
            *(uint2*)&OUT[(size_t)n * HC + c0] = *(const uint2*)tmp;
        }
    } else {
        if (half == 0) {
            float4 hv = make_float4(o0, o1, o2, o3);
            *(float4*)&hrow[w * HC + c0] = hv;
        }
        // wave-local final linear: no barrier (same-wave LDS write->read)
        int o = lane & 31, hh = lane >> 5;
        const float* hr = &hrow[w * HC + hh * 64];
        const float* wr = &wf_s[o * 132 + hh * 64];
        float acc = 0.f;
#pragma unroll
        for (int c = 0; c < 64; c += 4) {
            float4 hv = *(const float4*)&hr[c];
            float4 wv = *(const float4*)&wr[c];
            acc = fmaf(hv.x, wv.x, acc);
            acc = fmaf(hv.y, wv.y, acc);
            acc = fmaf(hv.z, wv.z, acc);
            acc = fmaf(hv.w, wv.w, acc);
        }
        acc += __shfl_xor(acc, 32);
        if (lane < 32) out2[(size_t)n * OUTC + o] = acc + bf[o];
    }
}

// ---------------------------------------------------------------------------
extern "C" void kernel_launch(void* const* d_in, const int* in_sizes, int n_in,
                              void* d_out, int out_size, void* d_ws, size_t ws_size,
                              hipStream_t stream)
{
    const float* x     = (const float*)d_in[0];
    const int*   esrc  = (const int*)d_in[1];
    const int*   edst  = (const int*)d_in[2];
    const float* eattr = (const float*)d_in[3];
    const float* Wl1 = (const float*)d_in[4];  const float* bl1 = (const float*)d_in[5];
    const float* Wr1 = (const float*)d_in[6];  const float* br1 = (const float*)d_in[7];
    const float* We1 = (const float*)d_in[8];  const float* att1 = (const float*)d_in[9];
    const float* b1  = (const float*)d_in[10];
    const float* Wl2 = (const float*)d_in[11]; const float* bl2 = (const float*)d_in[12];
    const float* Wr2 = (const float*)d_in[13]; const float* br2 = (const float*)d_in[14];
    const float* We2 = (const float*)d_in[15]; const float* att2 = (const float*)d_in[16];
    const float* b2  = (const float*)d_in[17];
    const float* Wf  = (const float*)d_in[18]; const float* bf  = (const float*)d_in[19];

    char* ws = (char*)d_ws;
    size_t off = 0;
    auto alloc = [&](size_t bytes) -> void* {
        void* p = ws + off;
        off += (bytes + 255) & ~(size_t)255;
        return p;
    };
    int*    cnt      = (int*)alloc((size_t)NNODES * 4);
    int*    offsets  = (int*)alloc((size_t)(NNODES + 1) * 4);
    int*    slot     = (int*)alloc((size_t)NEDGES * 4);
    uint4*  csr4     = (uint4*)alloc((size_t)NETOT * 16);
    int*    blocksum = (int*)alloc((size_t)NBLK * 4);
    __half* x16      = (__half*)alloc((size_t)NNODES * 64 * 2);
    __half* WH1      = (__half*)alloc((size_t)256 * 64 * 2);
    __half* WH2      = (__half*)alloc((size_t)256 * 128 * 2);
    __half* XL       = (__half*)alloc((size_t)NNODES * HC * 2);
    __half* XR       = (__half*)alloc((size_t)NNODES * HC * 2);
    __half* H1       = (__half*)alloc((size_t)NNODES * HC * 2);

    hipMemsetAsync(cnt, 0, (size_t)NNODES * 4, stream);

    count_convert_kernel<<<CB + (CONV + 255) / 256, 256, 0, stream>>>(
        edst, cnt, slot, x, Wl1, Wr1, Wl2, Wr2, x16, WH1, WH2);
    scan1_kernel<<<NBLK, 256, 0, stream>>>(cnt, offsets, blocksum);
    scan2_kernel<<<1, 256, 0, stream>>>(blocksum);
    scan3_kernel<<<NBLK, 256, 0, stream>>>(offsets, blocksum);

    // place (real edges, 16B pre-splat records) + layer-1 transform, fused
    place_transform_kernel<<<CB + NNODES / 32, 256, 0, stream>>>(
        esrc, edst, eattr, offsets, slot, csr4,
        x16, WH1, bl1, br1, XL, XR);
    loopattr_kernel<<<NBLK, 256, 0, stream>>>(offsets, csr4);

    // layer 1 aggregation
    agg_kernel<0><<<NNODES / 4, 256, 0, stream>>>(XL, XR, csr4, offsets,
                                                  We1, att1, b1, H1, nullptr, nullptr, nullptr);
    // layer 2 (+ fused final linear, wave-local)
    transform_mfma_kernel<128><<<NNODES / 32, 256, 0, stream>>>(H1, WH2, bl2, br2, XL, XR);
    agg_kernel<1><<<NNODES / 4, 256, 0, stream>>>(XL, XR, csr4, offsets,
                                                  We2, att2, b2, nullptr, Wf, bf, (float*)d_out);
}

// Round 20
// 177.774 us; speedup vs baseline: 1.0780x; 1.0780x over previous
//
#include <hip/hip_runtime.h>
#include <hip/hip_fp16.h>
#include <math.h>

#define NNODES 40000
#define NEDGES 640000
#define NETOT  (NEDGES + NNODES)
#define HC 128     // heads*channels
#define OUTC 32
#define NBLK   ((NNODES + 255) / 256)   // 157 scan blocks

typedef __attribute__((ext_vector_type(8))) _Float16 v8h;
typedef __attribute__((ext_vector_type(2))) _Float16 v2h;
typedef __attribute__((ext_vector_type(4))) float    v4f;

__device__ __forceinline__ v2h h2bits(unsigned u)
{
    union { unsigned u; v2h h; } c; c.u = u; return c.h;
}
__device__ __forceinline__ float h2f(unsigned short u)
{
    return __half2float(__ushort_as_half(u));
}
__device__ __forceinline__ unsigned hbits(float f)
{
    return (unsigned)__half_as_ushort(__float2half(f));
}

// ---------------------------------------------------------------------------
// Phase 0 (FUSED): blocks [0, CB) do per-dst counts + slot record;
// blocks [CB, ...) convert x / W matrices to fp16.
// ---------------------------------------------------------------------------
#define CB ((NEDGES + 255) / 256)                    // 2500 count blocks
#define SX4 (NNODES * 64 / 4)                        // float4 groups of x
#define CONV (SX4 + 2 * 128 * 64 + 2 * 128 * 128)    // convert elements

__global__ void count_convert_kernel(const int* __restrict__ dst, int* __restrict__ cnt,
                                     int* __restrict__ slot,
                                     const float* __restrict__ x,
                                     const float* __restrict__ Wl1, const float* __restrict__ Wr1,
                                     const float* __restrict__ Wl2, const float* __restrict__ Wr2,
                                     __half* __restrict__ x16,
                                     __half* __restrict__ WH1, __half* __restrict__ WH2)
{
    int b = blockIdx.x;
    if (b < CB) {
        int e = b * 256 + threadIdx.x;
        if (e >= NEDGES) return;
        slot[e] = atomicAdd(&cnt[dst[e]], 1);
        return;
    }
    int i = (b - CB) * 256 + threadIdx.x;
    if (i < SX4) {
        float4 v = ((const float4*)x)[i];
        __half tmp[4] = {__float2half(v.x), __float2half(v.y),
                         __float2half(v.z), __float2half(v.w)};
        ((uint2*)x16)[i] = *(const uint2*)tmp;
        return;
    }
    int j = i - SX4;
    if (j < 128 * 64)            { WH1[j] = __float2half(Wl1[j]); return; }
    j -= 128 * 64;
    if (j < 128 * 64)            { WH1[128 * 64 + j] = __float2half(Wr1[j]); return; }
    j -= 128 * 64;
    if (j < 128 * 128)           { WH2[j] = __float2half(Wl2[j]); return; }
    j -= 128 * 128;
    if (j < 128 * 128)           { WH2[128 * 128 + j] = __float2half(Wr2[j]); return; }
}

// ---------------------------------------------------------------------------
// Two-level exclusive scan of (cnt[n]+1) over 40000 nodes (+1 self slot).
// ---------------------------------------------------------------------------
__global__ __launch_bounds__(256) void scan1_kernel(const int* __restrict__ cnt,
                                                    int* __restrict__ offsets,
                                                    int* __restrict__ blocksum)
{
    __shared__ int s[256];
    int t = threadIdx.x;
    int n = blockIdx.x * 256 + t;
    int v = (n < NNODES) ? (cnt[n] + 1) : 0;   // +1 self loop
    s[t] = v;
    __syncthreads();
    for (int off = 1; off < 256; off <<= 1) {
        int u = (t >= off) ? s[t - off] : 0;
        __syncthreads();
        s[t] += u;
        __syncthreads();
    }
    if (n < NNODES) offsets[n] = s[t] - v;     // exclusive local prefix
    if (t == 255) blocksum[blockIdx.x] = s[255];
}

__global__ __launch_bounds__(256) void scan2_kernel(int* __restrict__ blocksum)
{
    __shared__ int s[256];
    int t = threadIdx.x;
    int v = (t < NBLK) ? blocksum[t] : 0;
    s[t] = v;
    __syncthreads();
    for (int off = 1; off < 256; off <<= 1) {
        int u = (t >= off) ? s[t - off] : 0;
        __syncthreads();
        s[t] += u;
        __syncthreads();
    }
    if (t < NBLK) blocksum[t] = s[t] - v;      // exclusive
}

__global__ __launch_bounds__(256) void scan3_kernel(int* __restrict__ offsets,
                                                    const int* __restrict__ blocksum)
{
    int n = blockIdx.x * 256 + threadIdx.x;
    if (n >= NNODES) return;
    offsets[n] += blocksum[blockIdx.x];
    if (n == 0) offsets[NNODES] = NETOT;
}

// ---------------------------------------------------------------------------
// MFMA node transform body: D[chan][node] = W(fp16)[chan][k] . X(fp16)[node][k]
// ---------------------------------------------------------------------------
template <int K>
__device__ __forceinline__ void transform_body(
    int bx, int t,
    const __half* __restrict__ X16, const __half* __restrict__ WH,
    const float* __restrict__ bl, const float* __restrict__ br,
    __half* __restrict__ XLo, __half* __restrict__ XRo)
{
    int w = t >> 6, lane = t & 63;
    int nb = bx * 32;
    int mb = w * 64;                 // channel base of this wave (0..192)
    int l15 = lane & 15, lg = lane >> 4;

    v4f acc[4][2];
#pragma unroll
    for (int mt = 0; mt < 4; mt++)
#pragma unroll
        for (int nt = 0; nt < 2; nt++) acc[mt][nt] = (v4f){0.f, 0.f, 0.f, 0.f};

#pragma unroll
    for (int kb = 0; kb < K; kb += 32) {
        int kf = kb + lg * 8;
        v8h bfr[2], afr[4];
#pragma unroll
        for (int nt = 0; nt < 2; nt++)
            bfr[nt] = *(const v8h*)&X16[(size_t)(nb + nt * 16 + l15) * K + kf];
#pragma unroll
        for (int mt = 0; mt < 4; mt++)
            afr[mt] = *(const v8h*)&WH[(size_t)(mb + mt * 16 + l15) * K + kf];
#pragma unroll
        for (int mt = 0; mt < 4; mt++)
#pragma unroll
            for (int nt = 0; nt < 2; nt++)
                acc[mt][nt] = __builtin_amdgcn_mfma_f32_16x16x32_f16(
                    afr[mt], bfr[nt], acc[mt][nt], 0, 0, 0);
    }

    bool isR = mb >= 128;                  // wave-uniform
    const float* bias = isR ? br : bl;
    __half* Out       = isR ? XRo : XLo;
    int cb = (mb & 127);
#pragma unroll
    for (int mt = 0; mt < 4; mt++) {
        int cc = cb + mt * 16 + lg * 4;    // 4 consecutive channels
        float b0 = bias[cc], b1 = bias[cc + 1], b2 = bias[cc + 2], b3 = bias[cc + 3];
#pragma unroll
        for (int nt = 0; nt < 2; nt++) {
            int n = nb + nt * 16 + l15;
            __half tmp[4] = {__float2half(acc[mt][nt][0] + b0),
                             __float2half(acc[mt][nt][1] + b1),
                             __float2half(acc[mt][nt][2] + b2),
                             __float2half(acc[mt][nt][3] + b3)};
            *(uint2*)&Out[(size_t)n * HC + cc] = *(const uint2*)tmp;
        }
    }
}

template <int K>
__global__ __launch_bounds__(256) void transform_mfma_kernel(
    const __half* __restrict__ X16, const __half* __restrict__ WH,
    const float* __restrict__ bl, const float* __restrict__ br,
    __half* __restrict__ XLo, __half* __restrict__ XRo)
{
    transform_body<K>(blockIdx.x, threadIdx.x, X16, WH, bl, br, XLo, XRo);
}

// ---------------------------------------------------------------------------
// Phase 2 (FUSED with layer-1 transform): blocks [0, CB) place real edges
// ATOMIC-FREE into CSR-by-dst as 8-byte uint2 records
//   {src | e0f16<<16,  e1f16 | e2f16<<16}
// Blocks [CB, CB+1250) run the K=64 MFMA transform.
// Self loop of node n lives at slot offsets[n+1]-1, written by agg1 inline.
// ---------------------------------------------------------------------------
__global__ __launch_bounds__(256) void place_transform_kernel(
    const int* __restrict__ src, const int* __restrict__ dst,
    const float* __restrict__ eattr,
    const int* __restrict__ offsets, const int* __restrict__ slot,
    uint2* __restrict__ csr2,
    const __half* __restrict__ X16, const __half* __restrict__ WH,
    const float* __restrict__ bl, const float* __restrict__ br,
    __half* __restrict__ XLo, __half* __restrict__ XRo)
{
    int b = blockIdx.x;
    if (b < CB) {
        int e = b * 256 + threadIdx.x;
        if (e >= NEDGES) return;
        int d = dst[e];
        int pos = offsets[d] + slot[e];
        uint2 rec;
        rec.x = (unsigned)src[e] | (hbits(eattr[e * 3 + 0]) << 16);
        rec.y = hbits(eattr[e * 3 + 1]) | (hbits(eattr[e * 3 + 2]) << 16);
        csr2[pos] = rec;
        return;
    }
    transform_body<64>(b - CB, threadIdx.x, X16, WH, bl, br, XLo, XRo);
}

// ---------------------------------------------------------------------------
// Cross-lane helpers, all DPP (VALU pipe, no lgkm wait).
// ---------------------------------------------------------------------------
template <int CTRL>
__device__ __forceinline__ float dpp_swap(float x)
{
    return __int_as_float(__builtin_amdgcn_update_dpp(
        0, __float_as_int(x), CTRL, 0xF, 0xF, true));
}

// ---------------------------------------------------------------------------
// GATv2 attention + aggregation, one wave per node, 8 independent
// accumulator states, packed-fp16 logits, no-max exp2 softmax, f32 accum.
// FUSE=0 (layer 1): also accumulates the three attr sums over real edges
// (SALU-decoded), processes the self loop inline with mean attrs, and
// WRITES the 8B self record into csr2[end-1] so agg2 consumes it as a
// normal edge (replaces the loopattr kernel; agg2 pays zero extra ops).
// FUSE=1 (layer 2): plain R17 path + wave-local fused final linear.
// ---------------------------------------------------------------------------
template <int FUSE>
__global__ __launch_bounds__(256) void agg_kernel(
    const __half* __restrict__ XL, const __half* __restrict__ XR,
    uint2* __restrict__ csr2, const int* __restrict__ offsets,
    const float* __restrict__ We, const float* __restrict__ att,
    const float* __restrict__ bias, __half* __restrict__ OUT,
    const float* __restrict__ Wf, const float* __restrict__ bf,
    float* __restrict__ out2)
{
    __shared__ float wf_s[FUSE ? OUTC * 132 : 1];   // pad 132 keeps rows 16B-aligned
    __shared__ float hrow[FUSE ? 4 * HC : 1];

    int t = threadIdx.x;
    if (FUSE) {
        for (int i = t * 4; i < OUTC * HC; i += 1024) {       // float4 staging
            float4 v = *(const float4*)&Wf[i];
            *(float4*)&wf_s[(i >> 7) * 132 + (i & 127)] = v;
        }
        __syncthreads();   // at kernel start: zero skew
    }

    int w = t >> 6;
    int n = __builtin_amdgcn_readfirstlane(blockIdx.x * 4 + w);
    int lane = t & 63;
    int c0 = lane * 2;

    const float LOG2E = 1.44269504088896340736f;
    v2h xr2 = *(const v2h*)&XR[(size_t)n * HC + c0];
    float2 atf = *(const float2*)&att[c0];
    v2h at2 = {(_Float16)(atf.x * LOG2E), (_Float16)(atf.y * LOG2E)};
    v2h we0 = {(_Float16)We[c0 * 3 + 0], (_Float16)We[c0 * 3 + 3]};
    v2h we1 = {(_Float16)We[c0 * 3 + 1], (_Float16)We[c0 * 3 + 4]};
    v2h we2 = {(_Float16)We[c0 * 3 + 2], (_Float16)We[c0 * 3 + 5]};
    const v2h vk02 = {(_Float16)0.2f, (_Float16)0.2f};

    int beg = offsets[n], end = offsets[n + 1];
    int lim = FUSE ? end : end - 1;          // agg1: real edges only

    float dacc[8], a0[8], a1[8];
#pragma unroll
    for (int i = 0; i < 8; i++) { dacc[i] = 0.f; a0[i] = 0.f; a1[i] = 0.f; }
    float as0 = 0.f, as1 = 0.f, as2 = 0.f;   // attr sums (agg1 only; DCE'd in agg2)

#define DECODE(q, s_, e00_, e11_, e22_)                                        \
    {                                                                          \
        unsigned qx = (unsigned)__builtin_amdgcn_readfirstlane((int)q.x);      \
        unsigned qy = (unsigned)__builtin_amdgcn_readfirstlane((int)q.y);      \
        s_   = (int)(qx & 0xffffu);                                            \
        e00_ = (qx >> 16) * 0x10001u;                                          \
        e11_ = (qy & 0xffffu) * 0x10001u;                                      \
        e22_ = (qy & 0xffff0000u) | (qy >> 16);                                \
        if (!FUSE) {                                                           \
            as0 += h2f((unsigned short)(qx >> 16));                            \
            as1 += h2f((unsigned short)(qy & 0xffffu));                        \
            as2 += h2f((unsigned short)(qy >> 16));                            \
        }                                                                      \
    }

#define EDGE_STEP(e00, e11, e22, xl2, d_, a0_, a1_)                            \
    {                                                                          \
        v2h m2 = xl2 + xr2;                                                    \
        m2 += we0 * h2bits(e00);                                               \
        m2 += we1 * h2bits(e11);                                               \
        m2 += we2 * h2bits(e22);                                               \
        v2h lk = m2 * vk02;                                                    \
        m2 = __builtin_elementwise_max(m2, lk);                                \
        float p;                                                               \
        p = __builtin_amdgcn_fdot2(m2, at2, 0.0f, false);                      \
        p += dpp_swap<0xB1>(p);                                                \
        p += dpp_swap<0x4E>(p);                                                \
        p += dpp_swap<0x141>(p);                                               \
        float ex = exp2f(p);                                                   \
        d_  += ex;                                                             \
        a0_ = fmaf(ex, (float)xl2.x, a0_);                                     \
        a1_ = fmaf(ex, (float)xl2.y, a1_);                                     \
    }

    int j = beg;
    for (; j + 7 < lim; j += 8) {
        uint2 q[8];
        v2h   xl[8];
        int      s[8];
        unsigned e00[8], e11[8], e22[8];
#pragma unroll
        for (int i = 0; i < 8; i++) q[i] = csr2[j + i];
#pragma unroll
        for (int i = 0; i < 8; i++) {
            DECODE(q[i], s[i], e00[i], e11[i], e22[i]);
            xl[i] = *(const v2h*)&XL[((size_t)s[i] << 7) + c0];
        }
#pragma unroll
        for (int i = 0; i < 8; i++)
            EDGE_STEP(e00[i], e11[i], e22[i], xl[i], dacc[i], a0[i], a1[i]);
    }
    if (j + 3 < lim) {
        uint2 q[4];
        v2h   xl[4];
        int      s[4];
        unsigned e00[4], e11[4], e22[4];
#pragma unroll
        for (int i = 0; i < 4; i++) q[i] = csr2[j + i];
#pragma unroll
        for (int i = 0; i < 4; i++) {
            DECODE(q[i], s[i], e00[i], e11[i], e22[i]);
            xl[i] = *(const v2h*)&XL[((size_t)s[i] << 7) + c0];
        }
#pragma unroll
        for (int i = 0; i < 4; i++)
            EDGE_STEP(e00[i], e11[i], e22[i], xl[i], dacc[i], a0[i], a1[i]);
        j += 4;
    }
    for (; j < lim; j++) {
        uint2 q = csr2[j];
        int s; unsigned e00, e11, e22;
        DECODE(q, s, e00, e11, e22);
        v2h xl = *(const v2h*)&XL[((size_t)s << 7) + c0];
        EDGE_STEP(e00, e11, e22, xl, dacc[0], a0[0], a1[0]);
    }

    if (!FUSE) {
        // self loop inline: mean of incoming attrs (0 if none), xl = own row;
        // also persist the 8B record for agg2.
        int c = lim - beg;
        float inv = (c > 0) ? (1.0f / (float)c) : 0.0f;
        unsigned h0 = hbits(as0 * inv), h1 = hbits(as1 * inv), h2 = hbits(as2 * inv);
        unsigned e00 = h0 * 0x10001u;
        unsigned e11 = h1 * 0x10001u;
        unsigned e22 = h2 * 0x10001u;
        v2h xl = *(const v2h*)&XL[(size_t)n * HC + c0];
        EDGE_STEP(e00, e11, e22, xl, dacc[0], a0[0], a1[0]);
        if (lane == 0) {
            uint2 rec;
            rec.x = (unsigned)n | (h0 << 16);
            rec.y = h1 | (h2 << 16);
            csr2[lim] = rec;
        }
    }
#undef EDGE_STEP
#undef DECODE

    float den  = ((dacc[0] + dacc[1]) + (dacc[2] + dacc[3])) +
                 ((dacc[4] + dacc[5]) + (dacc[6] + dacc[7]));
    float acc0 = ((a0[0] + a0[1]) + (a0[2] + a0[3])) +
                 ((a0[4] + a0[5]) + (a0[6] + a0[7]));
    float acc1 = ((a1[0] + a1[1]) + (a1[2] + a1[3])) +
                 ((a1[4] + a1[5]) + (a1[6] + a1[7]));

    float inv = 1.0f / (den + 1e-16f);
    float o0 = acc0 * inv + bias[c0];
    float o1 = acc1 * inv + bias[c0 + 1];
    o0 = (o0 > 0.f) ? o0 : expm1f(o0);   // ELU (both layers)
    o1 = (o1 > 0.f) ? o1 : expm1f(o1);

    if (!FUSE) {
        __half2 hv = __floats2half2_rn(o0, o1);
        *(__half2*)&OUT[(size_t)n * HC + c0] = hv;
    } else {
        // wave-local final linear: no barrier (same-wave LDS write->read)
        hrow[w * HC + c0]     = o0;
        hrow[w * HC + c0 + 1] = o1;
        int o = lane & 31, half = lane >> 5;
        const float* hr = &hrow[w * HC + half * 64];
        const float* wr = &wf_s[o * 132 + half * 64];
        float acc = 0.f;
#pragma unroll
        for (int c = 0; c < 64; c += 4) {
            float4 hv = *(const float4*)&hr[c];
            float4 wv = *(const float4*)&wr[c];
            acc = fmaf(hv.x, wv.x, acc);
            acc = fmaf(hv.y, wv.y, acc);
            acc = fmaf(hv.z, wv.z, acc);
            acc = fmaf(hv.w, wv.w, acc);
        }
        acc += __shfl_xor(acc, 32);
        if (lane < 32) out2[(size_t)n * OUTC + o] = acc + bf[o];
    }
}

// ---------------------------------------------------------------------------
extern "C" void kernel_launch(void* const* d_in, const int* in_sizes, int n_in,
                              void* d_out, int out_size, void* d_ws, size_t ws_size,
                              hipStream_t stream)
{
    const float* x     = (const float*)d_in[0];
    const int*   esrc  = (const int*)d_in[1];
    const int*   edst  = (const int*)d_in[2];
    const float* eattr = (const float*)d_in[3];
    const float* Wl1 = (const float*)d_in[4];  const float* bl1 = (const float*)d_in[5];
    const float* Wr1 = (const float*)d_in[6];  const float* br1 = (const float*)d_in[7];
    const float* We1 = (const float*)d_in[8];  const float* att1 = (const float*)d_in[9];
    const float* b1  = (const float*)d_in[10];
    const float* Wl2 = (const float*)d_in[11]; const float* bl2 = (const float*)d_in[12];
    const float* Wr2 = (const float*)d_in[13]; const float* br2 = (const float*)d_in[14];
    const float* We2 = (const float*)d_in[15]; const float* att2 = (const float*)d_in[16];
    const float* b2  = (const float*)d_in[17];
    const float* Wf  = (const float*)d_in[18]; const float* bf  = (const float*)d_in[19];

    char* ws = (char*)d_ws;
    size_t off = 0;
    auto alloc = [&](size_t bytes) -> void* {
        void* p = ws + off;
        off += (bytes + 255) & ~(size_t)255;
        return p;
    };
    int*    cnt      = (int*)alloc((size_t)NNODES * 4);
    int*    offsets  = (int*)alloc((size_t)(NNODES + 1) * 4);
    int*    slot     = (int*)alloc((size_t)NEDGES * 4);
    uint2*  csr2     = (uint2*)alloc((size_t)NETOT * 8);
    int*    blocksum = (int*)alloc((size_t)NBLK * 4);
    __half* x16      = (__half*)alloc((size_t)NNODES * 64 * 2);
    __half* WH1      = (__half*)alloc((size_t)256 * 64 * 2);
    __half* WH2      = (__half*)alloc((size_t)256 * 128 * 2);
    __half* XL       = (__half*)alloc((size_t)NNODES * HC * 2);
    __half* XR       = (__half*)alloc((size_t)NNODES * HC * 2);
    __half* H1       = (__half*)alloc((size_t)NNODES * HC * 2);

    hipMemsetAsync(cnt, 0, (size_t)NNODES * 4, stream);

    count_convert_kernel<<<CB + (CONV + 255) / 256, 256, 0, stream>>>(
        edst, cnt, slot, x, Wl1, Wr1, Wl2, Wr2, x16, WH1, WH2);
    scan1_kernel<<<NBLK, 256, 0, stream>>>(cnt, offsets, blocksum);
    scan2_kernel<<<1, 256, 0, stream>>>(blocksum);
    scan3_kernel<<<NBLK, 256, 0, stream>>>(offsets, blocksum);

    // place (real edges, 8B records) + layer-1 transform, fused
    place_transform_kernel<<<CB + NNODES / 32, 256, 0, stream>>>(
        esrc, edst, eattr, offsets, slot, csr2,
        x16, WH1, bl1, br1, XL, XR);

    // layer 1 aggregation (computes + persists self-loop records)
    agg_kernel<0><<<NNODES / 4, 256, 0, stream>>>(XL, XR, csr2, offsets,
                                                  We1, att1, b1, H1, nullptr, nullptr, nullptr);
    // layer 2 (+ fused final linear, wave-local)
    transform_mfma_kernel<128><<<NNODES / 32, 256, 0, stream>>>(H1, WH2, bl2, br2, XL, XR);
    agg_kernel<1><<<NNODES / 4, 256, 0, stream>>>(XL, XR, csr2, offsets,
                                                  We2, att2, b2, nullptr, Wf, bf, (float*)d_out);
}